// Round 7
// baseline (157.707 us; speedup 1.0000x reference)
//
#include <hip/hip_runtime.h>
#include <hip/hip_bf16.h>

#define N_TOKENS 8192
#define IN_FEAT 1024
#define OUT_FEAT 1024
#define NUM_EXPERT 8

#define BM 128
#define BN 128
#define BK 32

typedef __bf16 bf16x8 __attribute__((ext_vector_type(8)));
typedef float f32x4 __attribute__((ext_vector_type(4)));

// 8x fp32 -> bf16 (hardware v_cvt_pk_bf16_f32, RNE — compiler fuses pairs).
__device__ __forceinline__ bf16x8 cvt8(float4 lo, float4 hi) {
    bf16x8 r;
    r[0] = (__bf16)lo.x; r[1] = (__bf16)lo.y;
    r[2] = (__bf16)lo.z; r[3] = (__bf16)lo.w;
    r[4] = (__bf16)hi.x; r[5] = (__bf16)hi.y;
    r[6] = (__bf16)hi.z; r[7] = (__bf16)hi.w;
    return r;
}

// ---- single-block counting sort: ballot hist -> scan -> ballot-ranked scatter
// 256 threads, 32 tokens/thread, no atomics, no pre-zeroed memory needed.
__device__ __forceinline__ void sort_block256(const int* __restrict__ gate,
                                              int* __restrict__ perm,
                                              int* __restrict__ seg) {
    __shared__ int whist[4][NUM_EXPERT];
    __shared__ int wbase[4][NUM_EXPERT];
    const int t = threadIdx.x;
    const int wave = t >> 6, lane = t & 63;
    const unsigned long long lt = (lane == 0) ? 0ull : (~0ull >> (64 - lane));

    int4 v[8];
    #pragma unroll
    for (int j = 0; j < 8; ++j)
        v[j] = ((const int4*)gate)[j * 256 + t];   // tokens j*1024 + 4t + q

    // per-wave histogram via ballots (all indices compile-time static)
    int cnt[NUM_EXPERT];
    #pragma unroll
    for (int e = 0; e < NUM_EXPERT; ++e) cnt[e] = 0;
    #pragma unroll
    for (int j = 0; j < 8; ++j) {
        #pragma unroll
        for (int q = 0; q < 4; ++q) {
            const int g = (q == 0) ? v[j].x : (q == 1) ? v[j].y
                        : (q == 2) ? v[j].z : v[j].w;
            #pragma unroll
            for (int e = 0; e < NUM_EXPERT; ++e) {
                unsigned long long m = __ballot(g == e);
                cnt[e] += (int)__popcll(m);
            }
        }
    }
    if (lane == 0) {
        #pragma unroll
        for (int e = 0; e < NUM_EXPERT; ++e) whist[wave][e] = cnt[e];
    }
    __syncthreads();

    if (t == 0) {
        int s = 0;
        #pragma unroll
        for (int e = 0; e < NUM_EXPERT; ++e) {
            seg[e] = s;
            int b = s;
            #pragma unroll
            for (int w = 0; w < 4; ++w) { wbase[w][e] = b; b += whist[w][e]; }
            s = b;
        }
        seg[NUM_EXPERT] = s;
    }
    __syncthreads();

    // scatter: per-wave running offsets (uniform), ballot ranks within slot
    int off[NUM_EXPERT];
    #pragma unroll
    for (int e = 0; e < NUM_EXPERT; ++e) off[e] = wbase[wave][e];
    #pragma unroll
    for (int j = 0; j < 8; ++j) {
        #pragma unroll
        for (int q = 0; q < 4; ++q) {
            const int g = (q == 0) ? v[j].x : (q == 1) ? v[j].y
                        : (q == 2) ? v[j].z : v[j].w;
            const int tok = j * 1024 + t * 4 + q;
            #pragma unroll
            for (int e = 0; e < NUM_EXPERT; ++e) {
                unsigned long long m = __ballot(g == e);
                if (g == e) perm[off[e] + (int)__popcll(m & lt)] = tok;
                off[e] += (int)__popcll(m);
            }
        }
    }
}

__global__ __launch_bounds__(256) void moe_sort(const int* __restrict__ gate,
                                                int* __restrict__ perm,
                                                int* __restrict__ seg) {
    sort_block256(gate, perm, seg);
}

// ---- fused-convert bf16 grouped GEMM: reads fp32 inp/weight directly,
// converts in-register (hw cvt_pk_bf16_f32), stages into the same XOR-swizzled
// LDS layout the DMA version used (fragment reads unchanged). One barrier per
// BK=32 slab; loads for slab s+1 issue before the barrier (latency hides under
// the slab-s compute); convert+ds_write lands in the idle buffer after compute.
// bid = mtile*64 + ntile*8 + e => bid%8 = e pins each expert to one XCD: its
// 4 MB fp32 W + live A rows stay L2-resident across the 8/8 sharing blocks.
__global__ __launch_bounds__(256, 2) void moe_gemm_f(
    const float* __restrict__ inp,      // fp32 [8192][1024], token order
    const float* __restrict__ weight,   // fp32 [8][1024][1024]
    const int* __restrict__ perm,
    const int* __restrict__ seg,
    float* __restrict__ out) {

    const int bid = blockIdx.x;
    const int e = bid & 7;
    const int ntile = (bid >> 3) & 7;
    const int mtile = bid >> 6;

    const int base = seg[e];
    const int cnt = seg[e + 1] - base;
    if (mtile * BM >= cnt) return;
    const int tbase = base + mtile * BM;
    int rows = cnt - mtile * BM; if (rows > BM) rows = BM;

    __shared__ __align__(16) unsigned short lA[2][BM * BK];   // 2 x 8 KB
    __shared__ __align__(16) unsigned short lB[2][BN * BK];   // 2 x 8 KB

    const int t = threadIdx.x;

    // staging: chunk c in {t, t+256}: row = c>>2, k-part p = (c&3)^(row&3)
    const int crow = t >> 2;                 // 0..63
    const int p = (t & 3) ^ (crow & 3);
    int ar0 = tbase + crow;       if (ar0 > N_TOKENS - 1) ar0 = N_TOKENS - 1;
    int ar1 = tbase + 64 + crow;  if (ar1 > N_TOKENS - 1) ar1 = N_TOKENS - 1;
    const float* gA0 = inp + (size_t)perm[ar0] * IN_FEAT + p * 8;
    const float* gA1 = inp + (size_t)perm[ar1] * IN_FEAT + p * 8;
    const float* gB0 = weight + (size_t)e * (OUT_FEAT * IN_FEAT)
                       + (ntile * BN + crow) * IN_FEAT + p * 8;
    const float* gB1 = gB0 + 64 * IN_FEAT;
    const int dofs = t * 8;                  // chunk t
    const int dofs2 = (t + 256) * 8;         // chunk t+256

    // fragment read addresses (swizzle-matched)
    const int wave = t >> 6;
    const int lane = t & 63;
    const int wm = (wave & 1) << 6;
    const int wn = (wave >> 1) << 6;
    const int l15 = lane & 15;
    const int quad = lane >> 4;
    const int qx = quad ^ (l15 & 3);
    const int fofsA = (wm + l15) * BK + qx * 8;
    const int fofsB = (wn + l15) * BK + qx * 8;

    f32x4 acc[4][4];
    #pragma unroll
    for (int i = 0; i < 4; ++i)
        #pragma unroll
        for (int j = 0; j < 4; ++j)
            acc[i][j] = (f32x4)0.0f;

    float4 ra0, ra1, ra2, ra3, rb0, rb1, rb2, rb3;

    // prologue: slab 0 -> regs -> buf0
    ra0 = *(const float4*)(gA0);     ra1 = *(const float4*)(gA0 + 4);
    ra2 = *(const float4*)(gA1);     ra3 = *(const float4*)(gA1 + 4);
    rb0 = *(const float4*)(gB0);     rb1 = *(const float4*)(gB0 + 4);
    rb2 = *(const float4*)(gB1);     rb3 = *(const float4*)(gB1 + 4);
    *(bf16x8*)&lA[0][dofs]  = cvt8(ra0, ra1);
    *(bf16x8*)&lA[0][dofs2] = cvt8(ra2, ra3);
    *(bf16x8*)&lB[0][dofs]  = cvt8(rb0, rb1);
    *(bf16x8*)&lB[0][dofs2] = cvt8(rb2, rb3);

    #pragma unroll 1
    for (int s = 0; s < 32; ++s) {
        const int cur = s & 1;
        const int k0 = (s + 1) * BK;         // next slab (float offset)

        if (s < 31) {                        // issue next-slab loads EARLY
            ra0 = *(const float4*)(gA0 + k0);     ra1 = *(const float4*)(gA0 + k0 + 4);
            ra2 = *(const float4*)(gA1 + k0);     ra3 = *(const float4*)(gA1 + k0 + 4);
            rb0 = *(const float4*)(gB0 + k0);     rb1 = *(const float4*)(gB0 + k0 + 4);
            rb2 = *(const float4*)(gB1 + k0);     rb3 = *(const float4*)(gB1 + k0 + 4);
        }

        __syncthreads();   // buf[cur] writes visible; prior reads of buf[cur] done

        {
            bf16x8 af[4], bq[4];
            #pragma unroll
            for (int i = 0; i < 4; ++i)
                af[i] = *(const bf16x8*)&lA[cur][fofsA + i * 16 * BK];
            #pragma unroll
            for (int j = 0; j < 4; ++j)
                bq[j] = *(const bf16x8*)&lB[cur][fofsB + j * 16 * BK];
            #pragma unroll
            for (int i = 0; i < 4; ++i)
                #pragma unroll
                for (int j = 0; j < 4; ++j)
                    acc[i][j] = __builtin_amdgcn_mfma_f32_16x16x32_bf16(
                        af[i], bq[j], acc[i][j], 0, 0, 0);
        }

        if (s < 31) {      // convert + publish into the idle buffer
            *(bf16x8*)&lA[cur ^ 1][dofs]  = cvt8(ra0, ra1);
            *(bf16x8*)&lA[cur ^ 1][dofs2] = cvt8(ra2, ra3);
            *(bf16x8*)&lB[cur ^ 1][dofs]  = cvt8(rb0, rb1);
            *(bf16x8*)&lB[cur ^ 1][dofs2] = cvt8(rb2, rb3);
        }
    }

    // epilogue: C/D layout col=lane&15, row=quad*4+reg
    #pragma unroll
    for (int mi = 0; mi < 4; ++mi) {
        #pragma unroll
        for (int r = 0; r < 4; ++r) {
            int row = wm + mi * 16 + quad * 4 + r;
            if (row < rows) {
                int token = perm[tbase + row];
                float* op = out + token * OUT_FEAT + ntile * BN + wn;
                #pragma unroll
                for (int ni = 0; ni < 4; ++ni)
                    op[ni * 16 + l15] = acc[mi][ni][r];
            }
        }
    }
}

extern "C" void kernel_launch(void* const* d_in, const int* in_sizes, int n_in,
                              void* d_out, int out_size, void* d_ws, size_t ws_size,
                              hipStream_t stream) {
    const float* inp = (const float*)d_in[0];
    const int* gate = (const int*)d_in[1];
    const float* weight = (const float*)d_in[2];
    float* out = (float*)d_out;

    int* perm = (int*)d_ws;           // 8192 ints
    int* seg = perm + N_TOKENS;       // 9 (pad to 16)

    // 1-block counting sort (~2.5 us), then fused-convert grouped GEMM.
    moe_sort<<<1, 256, 0, stream>>>(gate, perm, seg);
    // bid = mtile*64 + ntile*8 + e ; 64 mtiles x 8 ntiles x 8 experts
    moe_gemm_f<<<4096, 256, 0, stream>>>(inp, weight, perm, seg, out);
}

// Round 8
// 147.895 us; speedup vs baseline: 1.0663x; 1.0663x over previous
//
#include <hip/hip_runtime.h>
#include <hip/hip_bf16.h>

#define N_TOKENS 8192
#define IN_FEAT 1024
#define OUT_FEAT 1024
#define NUM_EXPERT 8

#define BM 128
#define BN 128
#define BK 32

typedef __bf16 bf16x8 __attribute__((ext_vector_type(8)));
typedef float f32x4 __attribute__((ext_vector_type(4)));

// 8x fp32 -> bf16 (hardware v_cvt_pk_bf16_f32, RNE — compiler fuses pairs).
__device__ __forceinline__ bf16x8 cvt8(float4 lo, float4 hi) {
    bf16x8 r;
    r[0] = (__bf16)lo.x; r[1] = (__bf16)lo.y;
    r[2] = (__bf16)lo.z; r[3] = (__bf16)lo.w;
    r[4] = (__bf16)hi.x; r[5] = (__bf16)hi.y;
    r[6] = (__bf16)hi.z; r[7] = (__bf16)hi.w;
    return r;
}

// ---- single-block counting sort, SPILL-PROOF: no per-thread arrays at all.
// (R7 lesson: int4 v[8]/cnt[8]/off[8] got demoted to scratch -> 110 us.
//  Named scalars + macro-unrolled expert loop guarantee registers.)
// Ballot histogram -> t0 scan -> ballot-ranked scatter; gate read twice
// (2nd pass L2-hot). 256 threads, 32 tokens/thread, no atomics.

#define HIST1(G) do { int g_ = (G); unsigned long long m_;                   \
    m_ = __ballot(g_ == 0); c0 += (int)__popcll(m_);                         \
    m_ = __ballot(g_ == 1); c1 += (int)__popcll(m_);                         \
    m_ = __ballot(g_ == 2); c2 += (int)__popcll(m_);                         \
    m_ = __ballot(g_ == 3); c3 += (int)__popcll(m_);                         \
    m_ = __ballot(g_ == 4); c4 += (int)__popcll(m_);                         \
    m_ = __ballot(g_ == 5); c5 += (int)__popcll(m_);                         \
    m_ = __ballot(g_ == 6); c6 += (int)__popcll(m_);                         \
    m_ = __ballot(g_ == 7); c7 += (int)__popcll(m_); } while (0)

#define SCAT1(G, TOK) do { int g_ = (G); int tok_ = (TOK);                   \
    unsigned long long m_;                                                   \
    m_ = __ballot(g_ == 0);                                                  \
    if (g_ == 0) perm[o0 + (int)__popcll(m_ & lt)] = tok_;                   \
    o0 += (int)__popcll(m_);                                                 \
    m_ = __ballot(g_ == 1);                                                  \
    if (g_ == 1) perm[o1 + (int)__popcll(m_ & lt)] = tok_;                   \
    o1 += (int)__popcll(m_);                                                 \
    m_ = __ballot(g_ == 2);                                                  \
    if (g_ == 2) perm[o2 + (int)__popcll(m_ & lt)] = tok_;                   \
    o2 += (int)__popcll(m_);                                                 \
    m_ = __ballot(g_ == 3);                                                  \
    if (g_ == 3) perm[o3 + (int)__popcll(m_ & lt)] = tok_;                   \
    o3 += (int)__popcll(m_);                                                 \
    m_ = __ballot(g_ == 4);                                                  \
    if (g_ == 4) perm[o4 + (int)__popcll(m_ & lt)] = tok_;                   \
    o4 += (int)__popcll(m_);                                                 \
    m_ = __ballot(g_ == 5);                                                  \
    if (g_ == 5) perm[o5 + (int)__popcll(m_ & lt)] = tok_;                   \
    o5 += (int)__popcll(m_);                                                 \
    m_ = __ballot(g_ == 6);                                                  \
    if (g_ == 6) perm[o6 + (int)__popcll(m_ & lt)] = tok_;                   \
    o6 += (int)__popcll(m_);                                                 \
    m_ = __ballot(g_ == 7);                                                  \
    if (g_ == 7) perm[o7 + (int)__popcll(m_ & lt)] = tok_;                   \
    o7 += (int)__popcll(m_); } while (0)

__global__ __launch_bounds__(256) void moe_sort(const int* __restrict__ gate,
                                                int* __restrict__ perm,
                                                int* __restrict__ seg) {
    __shared__ int whist[4][NUM_EXPERT];
    __shared__ int wbase[4][NUM_EXPERT];
    const int t = threadIdx.x;
    const int wave = t >> 6, lane = t & 63;
    const unsigned long long lt = (lane == 0) ? 0ull : (~0ull >> (64 - lane));

    // pass 1: per-wave histogram (named scalars only)
    int c0 = 0, c1 = 0, c2 = 0, c3 = 0, c4 = 0, c5 = 0, c6 = 0, c7 = 0;
    #pragma unroll
    for (int j = 0; j < 8; ++j) {
        int4 vv = ((const int4*)gate)[j * 256 + t];   // tokens j*1024+4t+q
        HIST1(vv.x); HIST1(vv.y); HIST1(vv.z); HIST1(vv.w);
    }
    if (lane == 0) {
        whist[wave][0] = c0; whist[wave][1] = c1;
        whist[wave][2] = c2; whist[wave][3] = c3;
        whist[wave][4] = c4; whist[wave][5] = c5;
        whist[wave][6] = c6; whist[wave][7] = c7;
    }
    __syncthreads();

    if (t == 0) {
        int s = 0;
        #pragma unroll
        for (int e = 0; e < NUM_EXPERT; ++e) {
            seg[e] = s;
            int b = s;
            #pragma unroll
            for (int w = 0; w < 4; ++w) { wbase[w][e] = b; b += whist[w][e]; }
            s = b;
        }
        seg[NUM_EXPERT] = s;
    }
    __syncthreads();

    // pass 2: scatter with per-wave running offsets (named scalars only)
    int o0 = wbase[wave][0], o1 = wbase[wave][1];
    int o2 = wbase[wave][2], o3 = wbase[wave][3];
    int o4 = wbase[wave][4], o5 = wbase[wave][5];
    int o6 = wbase[wave][6], o7 = wbase[wave][7];
    #pragma unroll
    for (int j = 0; j < 8; ++j) {
        int4 vv = ((const int4*)gate)[j * 256 + t];   // L2-hot re-read
        const int tb = j * 1024 + t * 4;
        SCAT1(vv.x, tb);
        SCAT1(vv.y, tb + 1);
        SCAT1(vv.z, tb + 2);
        SCAT1(vv.w, tb + 3);
    }
}

// ---- fused-convert bf16 grouped GEMM: reads fp32 inp/weight directly,
// converts in-register (hw cvt_pk_bf16_f32), stages into the same XOR-swizzled
// LDS layout the DMA version used (fragment reads unchanged). One barrier per
// BK=32 slab; loads for slab s+1 issue before the barrier (latency hides under
// the slab-s compute); convert+ds_write lands in the idle buffer after compute.
// bid = mtile*64 + ntile*8 + e => bid%8 = e pins each expert to one XCD: its
// 4 MB fp32 W + live A rows stay L2-resident across the 8/8 sharing blocks.
__global__ __launch_bounds__(256, 2) void moe_gemm_f(
    const float* __restrict__ inp,      // fp32 [8192][1024], token order
    const float* __restrict__ weight,   // fp32 [8][1024][1024]
    const int* __restrict__ perm,
    const int* __restrict__ seg,
    float* __restrict__ out) {

    const int bid = blockIdx.x;
    const int e = bid & 7;
    const int ntile = (bid >> 3) & 7;
    const int mtile = bid >> 6;

    const int base = seg[e];
    const int cnt = seg[e + 1] - base;
    if (mtile * BM >= cnt) return;
    const int tbase = base + mtile * BM;
    int rows = cnt - mtile * BM; if (rows > BM) rows = BM;

    __shared__ __align__(16) unsigned short lA[2][BM * BK];   // 2 x 8 KB
    __shared__ __align__(16) unsigned short lB[2][BN * BK];   // 2 x 8 KB

    const int t = threadIdx.x;

    // staging: chunk c in {t, t+256}: row = c>>2, k-part p = (c&3)^(row&3)
    const int crow = t >> 2;                 // 0..63
    const int p = (t & 3) ^ (crow & 3);
    int ar0 = tbase + crow;       if (ar0 > N_TOKENS - 1) ar0 = N_TOKENS - 1;
    int ar1 = tbase + 64 + crow;  if (ar1 > N_TOKENS - 1) ar1 = N_TOKENS - 1;
    const float* gA0 = inp + (size_t)perm[ar0] * IN_FEAT + p * 8;
    const float* gA1 = inp + (size_t)perm[ar1] * IN_FEAT + p * 8;
    const float* gB0 = weight + (size_t)e * (OUT_FEAT * IN_FEAT)
                       + (ntile * BN + crow) * IN_FEAT + p * 8;
    const float* gB1 = gB0 + 64 * IN_FEAT;
    const int dofs = t * 8;                  // chunk t
    const int dofs2 = (t + 256) * 8;         // chunk t+256

    // fragment read addresses (swizzle-matched)
    const int wave = t >> 6;
    const int lane = t & 63;
    const int wm = (wave & 1) << 6;
    const int wn = (wave >> 1) << 6;
    const int l15 = lane & 15;
    const int quad = lane >> 4;
    const int qx = quad ^ (l15 & 3);
    const int fofsA = (wm + l15) * BK + qx * 8;
    const int fofsB = (wn + l15) * BK + qx * 8;

    f32x4 acc[4][4];
    #pragma unroll
    for (int i = 0; i < 4; ++i)
        #pragma unroll
        for (int j = 0; j < 4; ++j)
            acc[i][j] = (f32x4)0.0f;

    float4 ra0, ra1, ra2, ra3, rb0, rb1, rb2, rb3;

    // prologue: slab 0 -> regs -> buf0
    ra0 = *(const float4*)(gA0);     ra1 = *(const float4*)(gA0 + 4);
    ra2 = *(const float4*)(gA1);     ra3 = *(const float4*)(gA1 + 4);
    rb0 = *(const float4*)(gB0);     rb1 = *(const float4*)(gB0 + 4);
    rb2 = *(const float4*)(gB1);     rb3 = *(const float4*)(gB1 + 4);
    *(bf16x8*)&lA[0][dofs]  = cvt8(ra0, ra1);
    *(bf16x8*)&lA[0][dofs2] = cvt8(ra2, ra3);
    *(bf16x8*)&lB[0][dofs]  = cvt8(rb0, rb1);
    *(bf16x8*)&lB[0][dofs2] = cvt8(rb2, rb3);

    #pragma unroll 1
    for (int s = 0; s < 32; ++s) {
        const int cur = s & 1;
        const int k0 = (s + 1) * BK;         // next slab (float offset)

        if (s < 31) {                        // issue next-slab loads EARLY
            ra0 = *(const float4*)(gA0 + k0);     ra1 = *(const float4*)(gA0 + k0 + 4);
            ra2 = *(const float4*)(gA1 + k0);     ra3 = *(const float4*)(gA1 + k0 + 4);
            rb0 = *(const float4*)(gB0 + k0);     rb1 = *(const float4*)(gB0 + k0 + 4);
            rb2 = *(const float4*)(gB1 + k0);     rb3 = *(const float4*)(gB1 + k0 + 4);
        }

        __syncthreads();   // buf[cur] writes visible; prior reads of buf[cur] done

        {
            bf16x8 af[4], bq[4];
            #pragma unroll
            for (int i = 0; i < 4; ++i)
                af[i] = *(const bf16x8*)&lA[cur][fofsA + i * 16 * BK];
            #pragma unroll
            for (int j = 0; j < 4; ++j)
                bq[j] = *(const bf16x8*)&lB[cur][fofsB + j * 16 * BK];
            #pragma unroll
            for (int i = 0; i < 4; ++i)
                #pragma unroll
                for (int j = 0; j < 4; ++j)
                    acc[i][j] = __builtin_amdgcn_mfma_f32_16x16x32_bf16(
                        af[i], bq[j], acc[i][j], 0, 0, 0);
        }

        if (s < 31) {      // convert + publish into the idle buffer
            *(bf16x8*)&lA[cur ^ 1][dofs]  = cvt8(ra0, ra1);
            *(bf16x8*)&lA[cur ^ 1][dofs2] = cvt8(ra2, ra3);
            *(bf16x8*)&lB[cur ^ 1][dofs]  = cvt8(rb0, rb1);
            *(bf16x8*)&lB[cur ^ 1][dofs2] = cvt8(rb2, rb3);
        }
    }

    // epilogue: C/D layout col=lane&15, row=quad*4+reg
    #pragma unroll
    for (int mi = 0; mi < 4; ++mi) {
        #pragma unroll
        for (int r = 0; r < 4; ++r) {
            int row = wm + mi * 16 + quad * 4 + r;
            if (row < rows) {
                int token = perm[tbase + row];
                float* op = out + token * OUT_FEAT + ntile * BN + wn;
                #pragma unroll
                for (int ni = 0; ni < 4; ++ni)
                    op[ni * 16 + l15] = acc[mi][ni][r];
            }
        }
    }
}

extern "C" void kernel_launch(void* const* d_in, const int* in_sizes, int n_in,
                              void* d_out, int out_size, void* d_ws, size_t ws_size,
                              hipStream_t stream) {
    const float* inp = (const float*)d_in[0];
    const int* gate = (const int*)d_in[1];
    const float* weight = (const float*)d_in[2];
    float* out = (float*)d_out;

    int* perm = (int*)d_ws;           // 8192 ints
    int* seg = perm + N_TOKENS;       // 9 (pad to 16)

    // 1-block counting sort (~6 us, spill-proof), then fused-convert GEMM.
    moe_sort<<<1, 256, 0, stream>>>(gate, perm, seg);
    // bid = mtile*64 + ntile*8 + e ; 64 mtiles x 8 ntiles x 8 experts
    moe_gemm_f<<<4096, 256, 0, stream>>>(inp, weight, perm, seg, out);
}